// Round 9
// baseline (369.017 us; speedup 1.0000x reference)
//
#include <hip/hip_runtime.h>
#include <hip/hip_bf16.h>
#include <cfloat>

// Problem constants (reference: B=4, L=4096, D=1024, H=16, Dh=64)
#define BB 4
#define LL 4096
#define DD 1024
#define HH 16
#define DHH 64
#define MM (BB * LL)          // 16384 rows
#define LN_EPS 1e-5f
#define LDQVG 3072            // fused q|v|g row stride
#define SCC 16                // scan chunk length
#define NCHUNK (LL / SCC)     // 256 chunks per batch

typedef __hip_bfloat16 bf16;
typedef __attribute__((ext_vector_type(8))) short short8;
typedef __attribute__((ext_vector_type(4))) float f32x4;

struct bf16x4 { bf16 a, b, c, d; };
struct alignas(16) bf8 { bf16 e[8]; };

__device__ __forceinline__ float b2f(bf16 u) {
    union { unsigned int i; float f; } c;
    c.i = ((unsigned int)__bfloat16_as_ushort(u)) << 16;
    return c.f;
}

__device__ __forceinline__ float lam_of(const float* beta, int head) {
    float lam = 1.0f - exp2f(-beta[head]);
    return fminf(fmaxf(lam, 1.1754944e-38f), 1.0f - 1e-9f);
}

// ---------------------------------------------------------------------------
// All f32->bf16 conversions in ONE dispatch: x (16384 blocks) then the four
// weight matrices (4*1024 blocks) into contiguous wq|wv|wg|wo.
// ---------------------------------------------------------------------------
__global__ __launch_bounds__(256) void cvt_all(const float* __restrict__ x,
                                               const float* __restrict__ wq,
                                               const float* __restrict__ wv,
                                               const float* __restrict__ wg,
                                               const float* __restrict__ wo,
                                               bf16* __restrict__ xb,
                                               bf16* __restrict__ wb) {
    const int blk = blockIdx.x;
    const float* src;
    bf16* dst;
    size_t off;
    if (blk < 16384) {
        src = x; dst = xb; off = (size_t)blk * 1024;
    } else {
        int wblk  = blk - 16384;
        int which = wblk >> 10;
        src = (which == 0) ? wq : (which == 1) ? wv : (which == 2) ? wg : wo;
        dst = wb + (size_t)which * 1048576;
        off = (size_t)(wblk & 1023) * 1024;
    }
    size_t i = off + threadIdx.x * 4;
    float4 f = *(const float4*)(src + i);
    bf16x4 o;
    o.a = __float2bfloat16(f.x);
    o.b = __float2bfloat16(f.y);
    o.c = __float2bfloat16(f.z);
    o.d = __float2bfloat16(f.w);
    *(bf16x4*)(dst + i) = o;
}

// ---------------------------------------------------------------------------
// async 16B global -> LDS. NOTE: imm offset applies to BOTH global and LDS
// addresses — always pass 0, advance global pointers manually.
// ---------------------------------------------------------------------------
__device__ __forceinline__ void async16(const bf16* g, bf16* l) {
    __builtin_amdgcn_global_load_lds(
        (const __attribute__((address_space(1))) void*)g,
        (__attribute__((address_space(3))) void*)l,
        16, 0, 0);
}

// ---------------------------------------------------------------------------
// GEMM: C[M,N] = A[M,K] * B[N,K]^T  (row-major, K contiguous), ldc row stride.
//
// EXACT R4/R7 schedule (best measured: ~111us QVG, MfmaUtil 42, conflicts 0;
// R8's anti-phase stagger REFUTED, removed):
// 256x128 block tile, 256 threads = 4 waves (2M x 2N), wave 128x64 via
// 8x4 of v_mfma_f32_16x16x32_bf16 (acc 128 f32/lane).
//  - LDS ring-3 of BK=32 slots: A 16KB + B 8KB = 72KB -> 2 blocks/CU.
//  - ONE raw s_barrier per K-tile; counted vmcnt(6) steady state.
//  - swizzle: phys 16B-chunk = logical ^ ((row>>1)&3), 64B rows; read with
//    the 16x16 pattern (row = mult16 + (lane&15), chunk = lane>>4) = zero
//    conflicts (R1/R4 measured). Pre-swizzled global source + linear LDS
//    dest + swizzled ds_read (both-sides involution).
//
// R9: XCD-aware block swizzle (T1). Default round-robin puts same-B-panel
// neighbor blocks on different XCD L2s -> A panels re-fetched by all 24
// bn-groups (FETCH 78MB vs 38MB ideal). Bijective remap (nwg%8==0 for both
// launches): wg = (lin&7)*(nwg/8) + (lin>>3); gridDim.x == 64 in both
// launches so bm = wg&63, bn = wg>>6.
//
// V-column blocks (QVG launch) also emit per-chunk decay-weighted sums S
// from the f32 accumulators (R7, replaces scan_chunksum).
// ---------------------------------------------------------------------------
template <typename OutT, int KK>
__global__ __launch_bounds__(256, 2) void gemm_ring(const bf16* __restrict__ A,
                                                    const bf16* __restrict__ Bm,
                                                    OutT* __restrict__ C,
                                                    int ldc,
                                                    float* __restrict__ Sout,
                                                    const float* __restrict__ beta) {
    constexpr int BK    = 32;
    constexpr int NT    = KK / BK;        // 32 K-tiles
    constexpr int ASLOT = 256 * BK;       // 8192 elems = 16 KB
    constexpr int BSLOT = 128 * BK;       // 4096 elems =  8 KB

    __shared__ alignas(16) bf16 sA[3 * ASLOT];   // 48 KB
    __shared__ alignas(16) bf16 sB[3 * BSLOT];   // 24 KB

    const int t    = threadIdx.x;
    const int lane = t & 63;
    const int wave = t >> 6;
    const int wm   = wave >> 1;          // 0..1 (M half: 128 rows)
    const int wn   = wave & 1;           // 0..1 (N half: 64 cols)

    // ---- XCD-aware bijective block swizzle (R9). gridDim.x == 64.
    const int lin = blockIdx.x + (blockIdx.y << 6);
    const int nwg = (gridDim.x * gridDim.y);
    const int wg  = (lin & 7) * (nwg >> 3) + (lin >> 3);
    const int bm  = wg & 63;
    const int bn  = wg >> 6;

    // ---- staging: thread t owns phys chunk t&3 of row t>>2 (+j*64 rows).
    const int srow = t >> 2;
    const int cswz = ((t & 3) ^ ((srow >> 1) & 3)) * 8;
    const bf16* gA = A  + (size_t)(bm * 256 + srow) * KK + cswz;
    const bf16* gB = Bm + (size_t)(bn * 128 + srow) * KK + cswz;
    const size_t rstep = (size_t)64 * KK;        // +64 rows
    bf16* const lA = sA + t * 8;
    bf16* const lB = sB + t * 8;

    // ---- ds_read addressing (R1/R4-verified zero-conflict 16x16 pattern)
    const int f16  = lane & 15;
    const int swz8 = ((lane >> 4) ^ ((f16 >> 1) & 3)) * 8;
    const bf16* const rdA0 = sA + (wm * 128 + f16) * BK + swz8;  // +mi*512
    const bf16* const rdB0 = sB + (wn * 64  + f16) * BK + swz8;  // +ni*512

    f32x4 acc[8][4] = {};

    // slot element-offsets: slR = slot(T), slS = slot(T+2) (rotate mod 3)
    int slR = 0,         slR2 = 0;
    int slS = 2 * ASLOT, slS2 = 2 * BSLOT;

    // ---- prologue: stage tiles 0,1; retire tile 0 (vmcnt 12->6); publish.
#pragma unroll
    for (int j = 0; j < 4; ++j) async16(gA + j * rstep, lA + j * 2048);
#pragma unroll
    for (int j = 0; j < 2; ++j) async16(gB + j * rstep, lB + j * 2048);
    gA += BK; gB += BK;
#pragma unroll
    for (int j = 0; j < 4; ++j) async16(gA + j * rstep, lA + ASLOT + j * 2048);
#pragma unroll
    for (int j = 0; j < 2; ++j) async16(gB + j * rstep, lB + BSLOT + j * 2048);
    gA += BK; gB += BK;
    asm volatile("s_waitcnt vmcnt(6)" ::: "memory");
    __builtin_amdgcn_s_barrier();

#define TILE(DOSTAGE, VMN)                                                     \
  {                                                                            \
    short8 a[8], b[4];                                                         \
    a[0] = *(const short8*)(rdA0 + slR);                                       \
    _Pragma("unroll") for (int ni = 0; ni < 4; ++ni)                           \
        b[ni] = *(const short8*)(rdB0 + ni * 512 + slR2);                      \
    _Pragma("unroll") for (int mi = 1; mi < 8; ++mi)                           \
        a[mi] = *(const short8*)(rdA0 + mi * 512 + slR);                       \
    if (DOSTAGE) {                                                             \
      _Pragma("unroll") for (int j = 0; j < 4; ++j)                            \
          async16(gA + j * rstep, lA + slS + j * 2048);                        \
      _Pragma("unroll") for (int j = 0; j < 2; ++j)                            \
          async16(gB + j * rstep, lB + slS2 + j * 2048);                       \
      gA += BK; gB += BK;                                                      \
    }                                                                          \
    __builtin_amdgcn_s_setprio(1);                                             \
    _Pragma("unroll") for (int mi = 0; mi < 8; ++mi)                           \
      _Pragma("unroll") for (int ni = 0; ni < 4; ++ni)                         \
        acc[mi][ni] = __builtin_amdgcn_mfma_f32_16x16x32_bf16(                 \
            a[mi], b[ni], acc[mi][ni], 0, 0, 0);                               \
    __builtin_amdgcn_s_setprio(0);                                             \
    if ((VMN) == 6)      asm volatile("s_waitcnt vmcnt(6)" ::: "memory");      \
    else if ((VMN) == 0) asm volatile("s_waitcnt vmcnt(0)" ::: "memory");      \
    if ((VMN) >= 0) __builtin_amdgcn_s_barrier();                              \
    slR  = (slR  == 2 * ASLOT) ? 0 : slR  + ASLOT;                             \
    slR2 = (slR2 == 2 * BSLOT) ? 0 : slR2 + BSLOT;                             \
    slS  = (slS  == 2 * ASLOT) ? 0 : slS  + ASLOT;                             \
    slS2 = (slS2 == 2 * BSLOT) ? 0 : slS2 + BSLOT;                             \
  }

    // main loop: T = 0..NT-3 stage tiles 2..NT-1, counted vmcnt(6)
#pragma unroll 1
    for (int T = 0; T < NT - 2; ++T) {
        TILE(true, 6);
    }
    TILE(false, 0);    // T = NT-2: drain tile NT-1's loads
    TILE(false, -1);   // T = NT-1: no sync, fall through to epilogue

#undef TILE

    // epilogue: 16x16 C/D layout: col = lane&15, row = (lane>>4)*4 + reg
    const int col0 = bn * 128 + wn * 64 + (lane & 15);
    const int row0 = bm * 256 + wm * 128 + ((lane >> 4) * 4);
#pragma unroll
    for (int mi = 0; mi < 8; ++mi) {
#pragma unroll
        for (int ni = 0; ni < 4; ++ni) {
#pragma unroll
            for (int r = 0; r < 4; ++r) {
                int row = row0 + mi * 16 + r;
                C[(size_t)row * ldc + col0 + ni * 16] = (OutT)acc[mi][ni][r];
            }
        }
    }

    // ---- fused chunk-sum epilogue (QVG launch, V columns only) ----
    if (Sout && bn >= 8 && bn < 16) {
        const int p0 = (lane >> 4) * 4;            // intra-chunk base position
        const int bglob = bm >> 4;                 // batch (4096 rows = 16 bm)
        const int c0 = ((bm & 15) * 16 + wm * 8);  // chunk idx of mi=0
#pragma unroll
        for (int ni = 0; ni < 4; ++ni) {
            const int f = col0 + ni * 16 - 1024;   // v-feature index [0,1024)
            const float lam = lam_of(beta, f >> 6);
            const float l2g = __log2f(lam);
            float w[4];
#pragma unroll
            for (int r = 0; r < 4; ++r)
                w[r] = exp2f((float)(15 - p0 - r) * l2g);
#pragma unroll
            for (int mi = 0; mi < 8; ++mi) {
                float part = 0.0f;
#pragma unroll
                for (int r = 0; r < 4; ++r)
                    part = fmaf(w[r], acc[mi][ni][r], part);
                part += __shfl_xor(part, 16, 64);
                part += __shfl_xor(part, 32, 64);
                if (p0 == 0) {                     // lanes 0..15 write
                    const int cg = c0 + mi;
                    Sout[((size_t)bglob * NCHUNK + cg) * DD + f] = part;
                }
            }
        }
    }
}

// ---------------------------------------------------------------------------
// Serial carry over 256 chunks (R7 version — R8's 3-kernel hierarchy was
// ~4us WORSE from launch overhead + W/TS round-trip; reverted).
// 16-wide load prefetch; loads for batch i+1 independent of the recurrence.
// ---------------------------------------------------------------------------
__global__ __launch_bounds__(64) void scan_carry(const float* __restrict__ S,
                                                 float* __restrict__ T,
                                                 const float* __restrict__ beta) {
    const int gid = blockIdx.x * 64 + threadIdx.x;  // 0..4095
    const int b = gid >> 10;
    const int f = gid & 1023;
    const float lam  = lam_of(beta, f >> 6);
    const float lamC = powf(lam, (float)SCC);

    const size_t base = (size_t)b * NCHUNK * DD + f;

    float v[16];
#pragma unroll
    for (int j = 0; j < 16; ++j) v[j] = S[base + (size_t)j * DD];

    float t = 0.0f;
    for (int c0 = 0; c0 < NCHUNK; c0 += 16) {
        float cur[16];
#pragma unroll
        for (int j = 0; j < 16; ++j) cur[j] = v[j];
        if (c0 + 16 < NCHUNK) {
#pragma unroll
            for (int j = 0; j < 16; ++j)
                v[j] = S[base + (size_t)(c0 + 16 + j) * DD];
        }
#pragma unroll
        for (int j = 0; j < 16; ++j) {
            T[base + (size_t)(c0 + j) * DD] = t;
            t = fmaf(t, lamC, cur[j]);
        }
    }
}

// ---------------------------------------------------------------------------
// Fused: re-scan chunk from carry T -> ret (kept in LDS), per-row LayerNorm,
// SiLU gate, write z (bf16, contiguous [M,1024]). ret never touches HBM.
// grid (NCHUNK, BB), 128 threads (2 waves). LDS 16 rows x 1024 bf16 = 32KB.
// R9: phase-1 prefetch depth 2 (was 1) — deeper MLP on the 16-row serial
// scan chain (kernel is latency-bound at 8 waves/CU).
// ---------------------------------------------------------------------------
__global__ __launch_bounds__(128) void scan_apply_ln(const bf16* __restrict__ qvg,
                                                     const float* __restrict__ beta,
                                                     const float* __restrict__ T,
                                                     const float* __restrict__ gamma,
                                                     const float* __restrict__ betaln,
                                                     bf16* __restrict__ z) {
    __shared__ bf16 lds_ret[SCC][DD];   // 32 KB

    const int c   = blockIdx.x;
    const int b   = blockIdx.y;
    const int tid = threadIdx.x;        // 0..127
    const int f0  = tid * 8;
    const float lam = lam_of(beta, f0 >> 6);

    // ---- phase 1: local scan from carry, ret -> LDS ----
    const float* tp = T + ((size_t)(b * NCHUNK + c)) * DD + f0;
    float4 lo = *(const float4*)(tp);
    float4 hi = *(const float4*)(tp + 4);
    float s[8] = {lo.x, lo.y, lo.z, lo.w, hi.x, hi.y, hi.z, hi.w};

    const bf16* qp = qvg + ((size_t)(b * LL + c * SCC)) * LDQVG + f0;
    bf8 vbuf[2], qbuf[2];
    vbuf[0] = *(const bf8*)(qp + 1024);
    qbuf[0] = *(const bf8*)(qp);
    vbuf[1] = *(const bf8*)(qp + 1024 + LDQVG);
    qbuf[1] = *(const bf8*)(qp + LDQVG);
#pragma unroll
    for (int t = 0; t < SCC; ++t) {
        bf8 vv = vbuf[t & 1];
        bf8 qq = qbuf[t & 1];
        if (t + 2 < SCC) {
            const size_t offn = (size_t)(t + 2) * LDQVG;
            vbuf[t & 1] = *(const bf8*)(qp + 1024 + offn);
            qbuf[t & 1] = *(const bf8*)(qp + offn);
        }
        bf8 o;
#pragma unroll
        for (int j = 0; j < 8; ++j) {
            s[j] = fmaf(s[j], lam, b2f(vv.e[j]));
            o.e[j] = __float2bfloat16(b2f(qq.e[j]) * s[j]);
        }
        *(bf8*)(&lds_ret[t][f0]) = o;
    }
    __syncthreads();

    // ---- phase 2: per-row LN + SiLU gate. wave w does rows w, w+2, ... ----
    const int lane = tid & 63;
    const int wv   = tid >> 6;

    // prefetch gate rows for all 8 iterations (independent HBM loads)
    bf8 gAp[8], gBp[8];
#pragma unroll
    for (int i = 0; i < 8; ++i) {
        const size_t row = (size_t)(b * LL + c * SCC + wv + 2 * i);
        const bf16* gp = qvg + row * LDQVG + 2048 + lane * 8;
        gAp[i] = *(const bf8*)(gp);
        gBp[i] = *(const bf8*)(gp + 512);
    }

    // cache gamma/beta for this lane's two feature groups (lane*8, 512+lane*8)
    float gmA[8], btA[8], gmB[8], btB[8];
#pragma unroll
    for (int j = 0; j < 8; j += 4) {
        *(float4*)(gmA + j) = *(const float4*)(gamma  + lane * 8 + j);
        *(float4*)(btA + j) = *(const float4*)(betaln + lane * 8 + j);
        *(float4*)(gmB + j) = *(const float4*)(gamma  + 512 + lane * 8 + j);
        *(float4*)(btB + j) = *(const float4*)(betaln + 512 + lane * 8 + j);
    }

#pragma unroll
    for (int i = 0; i < 8; ++i) {
        const int t = wv + 2 * i;
        bf8 rA = *(const bf8*)(&lds_ret[t][lane * 8]);
        bf8 rB = *(const bf8*)(&lds_ret[t][512 + lane * 8]);

        float xa[8], xb2[8];
        float sum = 0.f, sq = 0.f;
#pragma unroll
        for (int j = 0; j < 8; ++j) {
            xa[j]  = b2f(rA.e[j]);
            xb2[j] = b2f(rB.e[j]);
            sum += xa[j] + xb2[j];
            sq  += xa[j] * xa[j] + xb2[j] * xb2[j];
        }
#pragma unroll
        for (int off = 32; off >= 1; off >>= 1) {
            sum += __shfl_xor(sum, off, 64);
            sq  += __shfl_xor(sq,  off, 64);
        }
        const float mu   = sum * (1.0f / DD);
        const float var  = sq * (1.0f / DD) - mu * mu;
        const float rstd = rsqrtf(var + LN_EPS);

        bf8 oA, oB;
#pragma unroll
        for (int j = 0; j < 8; ++j) {
            float ya = (xa[j]  - mu) * rstd * gmA[j] + btA[j];
            float yb = (xb2[j] - mu) * rstd * gmB[j] + btB[j];
            float ga = b2f(gAp[i].e[j]);
            float gb = b2f(gBp[i].e[j]);
            oA.e[j] = __float2bfloat16(ya * (ga / (1.0f + expf(-ga))));
            oB.e[j] = __float2bfloat16(yb * (gb / (1.0f + expf(-gb))));
        }
        const size_t row = (size_t)(b * LL + c * SCC + t);
        bf16* zp = z + row * DD + lane * 8;
        *(bf8*)(zp)       = oA;
        *(bf8*)(zp + 512) = oB;
    }
}

// ---------------------------------------------------------------------------
// launch
// ---------------------------------------------------------------------------
extern "C" void kernel_launch(void* const* d_in, const int* in_sizes, int n_in,
                              void* d_out, int out_size, void* d_ws, size_t ws_size,
                              hipStream_t stream) {
    const float* x     = (const float*)d_in[0];
    const float* Wq    = (const float*)d_in[1];
    const float* Wv    = (const float*)d_in[2];
    const float* Wo    = (const float*)d_in[3];
    const float* Wg    = (const float*)d_in[4];
    const float* beta  = (const float*)d_in[5];
    const float* ln_g  = (const float*)d_in[6];
    const float* ln_b  = (const float*)d_in[7];
    float* out = (float*)d_out;

    char* ws = (char*)d_ws;
    // workspace (136MB, time-multiplexed):
    //   @0    : xb 32MB (cvt -> QVG GEMM) -> zb 32MB (apply_ln -> final GEMM)
    //   @32MB : wqb 6MB (wq|wv|wg; dead after QVG GEMM) -> Tbuf 4MB
    //   @38MB : wob 2MB (live until final GEMM)
    //   @40MB : qvg 96MB [M,3072] = q|v|g per row
    // S (4MB f32) lives in d_out: written by QVG epilogue, consumed by carry,
    // dead before the final GEMM overwrites all of out.
    bf16*  xb   = (bf16*)ws;
    bf16*  wqb  = (bf16*)(ws + (size_t)32 * 1024 * 1024);
    float* Tbuf = (float*)(ws + (size_t)32 * 1024 * 1024);     // alias wqb (dead)
    bf16*  wob  = wqb + 3 * 1048576;
    bf16*  qvg  = (bf16*)(ws + (size_t)40 * 1024 * 1024);
    bf16*  zb   = xb;
    float* Sbuf = out;                                         // scratch in d_out

    // all dtype conversions in one dispatch (x + 4 weights)
    cvt_all<<<dim3(16384 + 4096), dim3(256), 0, stream>>>(x, Wq, Wv, Wg, Wo, xb, wqb);

    // fused QVG GEMM: [M,1024] x [3072,1024]^T -> [M,3072]; V-blocks also
    // emit chunk sums S directly from f32 accumulators.
    gemm_ring<bf16, DD><<<dim3(MM / 256, LDQVG / 128), dim3(256), 0, stream>>>(
        xb, wqb, qvg, LDQVG, Sbuf, beta);

    // carry scan over chunks, then fused re-scan + LN + gate
    scan_carry<<<dim3(64), dim3(64), 0, stream>>>(Sbuf, Tbuf, beta);
    scan_apply_ln<<<dim3(NCHUNK, BB), dim3(128), 0, stream>>>(
        qvg, beta, Tbuf, ln_g, ln_b, zb);

    // final GEMM: [M,1024] x [1024,1024]^T -> [M,1024] f32 (overwrites out)
    gemm_ring<float, DD><<<dim3(MM / 256, DD / 128), dim3(256), 0, stream>>>(
        zb, wob, out, DD, nullptr, nullptr);
}

// Round 10
// 311.449 us; speedup vs baseline: 1.1848x; 1.1848x over previous
//
#include <hip/hip_runtime.h>
#include <hip/hip_bf16.h>
#include <cfloat>

// Problem constants (reference: B=4, L=4096, D=1024, H=16, Dh=64)
#define BB 4
#define LL 4096
#define DD 1024
#define HH 16
#define DHH 64
#define MM (BB * LL)          // 16384 rows
#define LN_EPS 1e-5f
#define LDQVG 3072            // fused q|v|g row stride
#define SCC 16                // scan chunk length
#define NCHUNK (LL / SCC)     // 256 chunks per batch

typedef __hip_bfloat16 bf16;
typedef __attribute__((ext_vector_type(8))) short short8;
typedef __attribute__((ext_vector_type(4))) float f32x4;

struct bf16x4 { bf16 a, b, c, d; };
struct alignas(16) bf8 { bf16 e[8]; };
struct alignas(8)  bf4 { bf16 e[4]; };

__device__ __forceinline__ float b2f(bf16 u) {
    union { unsigned int i; float f; } c;
    c.i = ((unsigned int)__bfloat16_as_ushort(u)) << 16;
    return c.f;
}

__device__ __forceinline__ float lam_of(const float* beta, int head) {
    float lam = 1.0f - exp2f(-beta[head]);
    return fminf(fmaxf(lam, 1.1754944e-38f), 1.0f - 1e-9f);
}

// ---------------------------------------------------------------------------
// All f32->bf16 conversions in ONE dispatch: x (16384 blocks) then the four
// weight matrices (4*1024 blocks) into contiguous wq|wv|wg|wo.
// ---------------------------------------------------------------------------
__global__ __launch_bounds__(256) void cvt_all(const float* __restrict__ x,
                                               const float* __restrict__ wq,
                                               const float* __restrict__ wv,
                                               const float* __restrict__ wg,
                                               const float* __restrict__ wo,
                                               bf16* __restrict__ xb,
                                               bf16* __restrict__ wb) {
    const int blk = blockIdx.x;
    const float* src;
    bf16* dst;
    size_t off;
    if (blk < 16384) {
        src = x; dst = xb; off = (size_t)blk * 1024;
    } else {
        int wblk  = blk - 16384;
        int which = wblk >> 10;
        src = (which == 0) ? wq : (which == 1) ? wv : (which == 2) ? wg : wo;
        dst = wb + (size_t)which * 1048576;
        off = (size_t)(wblk & 1023) * 1024;
    }
    size_t i = off + threadIdx.x * 4;
    float4 f = *(const float4*)(src + i);
    bf16x4 o;
    o.a = __float2bfloat16(f.x);
    o.b = __float2bfloat16(f.y);
    o.c = __float2bfloat16(f.z);
    o.d = __float2bfloat16(f.w);
    *(bf16x4*)(dst + i) = o;
}

// ---------------------------------------------------------------------------
// async 16B global -> LDS. NOTE: imm offset applies to BOTH global and LDS
// addresses — always pass 0, advance global pointers manually.
// ---------------------------------------------------------------------------
__device__ __forceinline__ void async16(const bf16* g, bf16* l) {
    __builtin_amdgcn_global_load_lds(
        (const __attribute__((address_space(1))) void*)g,
        (__attribute__((address_space(3))) void*)l,
        16, 0, 0);
}

// ---------------------------------------------------------------------------
// GEMM: C[M,N] = A[M,K] * B[N,K]^T  (row-major, K contiguous), ldc row stride.
//
// EXACT R7 schedule (best measured: ~111us QVG, MfmaUtil 42, conflicts 0).
// R9's XCD swizzle REFUTED (FETCH 78->398MB: default lin%8=bm%8 already gives
// each XCD an L2-resident 4MB A-slice; remap forced 32MB A streaming) — gone.
// R8's anti-phase stagger REFUTED — gone.
// 256x128 block tile, 256 threads = 4 waves (2M x 2N), wave 128x64 via
// 8x4 of v_mfma_f32_16x16x32_bf16 (acc 128 f32/lane).
//  - LDS ring-3 of BK=32 slots: A 16KB + B 8KB = 72KB -> 2 blocks/CU.
//  - ONE raw s_barrier per K-tile; counted vmcnt(6) steady state.
//  - swizzle: phys 16B-chunk = logical ^ ((row>>1)&3), 64B rows; read with
//    the 16x16 pattern (row = mult16 + (lane&15), chunk = lane>>4) = zero
//    conflicts (R1/R4 measured). Pre-swizzled global source + linear LDS
//    dest + swizzled ds_read (both-sides involution).
//
// V-column blocks (QVG launch) also emit per-chunk decay-weighted sums S
// from the f32 accumulators (R7, replaces scan_chunksum).
// ---------------------------------------------------------------------------
template <typename OutT, int KK>
__global__ __launch_bounds__(256, 2) void gemm_ring(const bf16* __restrict__ A,
                                                    const bf16* __restrict__ Bm,
                                                    OutT* __restrict__ C,
                                                    int ldc,
                                                    float* __restrict__ Sout,
                                                    const float* __restrict__ beta) {
    constexpr int BK    = 32;
    constexpr int NT    = KK / BK;        // 32 K-tiles
    constexpr int ASLOT = 256 * BK;       // 8192 elems = 16 KB
    constexpr int BSLOT = 128 * BK;       // 4096 elems =  8 KB

    __shared__ alignas(16) bf16 sA[3 * ASLOT];   // 48 KB
    __shared__ alignas(16) bf16 sB[3 * BSLOT];   // 24 KB

    const int t    = threadIdx.x;
    const int lane = t & 63;
    const int wave = t >> 6;
    const int wm   = wave >> 1;          // 0..1 (M half: 128 rows)
    const int wn   = wave & 1;           // 0..1 (N half: 64 cols)
    const int bm   = blockIdx.x;
    const int bn   = blockIdx.y;

    // ---- staging: thread t owns phys chunk t&3 of row t>>2 (+j*64 rows).
    const int srow = t >> 2;
    const int cswz = ((t & 3) ^ ((srow >> 1) & 3)) * 8;
    const bf16* gA = A  + (size_t)(bm * 256 + srow) * KK + cswz;
    const bf16* gB = Bm + (size_t)(bn * 128 + srow) * KK + cswz;
    const size_t rstep = (size_t)64 * KK;        // +64 rows
    bf16* const lA = sA + t * 8;
    bf16* const lB = sB + t * 8;

    // ---- ds_read addressing (R1/R4-verified zero-conflict 16x16 pattern)
    const int f16  = lane & 15;
    const int swz8 = ((lane >> 4) ^ ((f16 >> 1) & 3)) * 8;
    const bf16* const rdA0 = sA + (wm * 128 + f16) * BK + swz8;  // +mi*512
    const bf16* const rdB0 = sB + (wn * 64  + f16) * BK + swz8;  // +ni*512

    f32x4 acc[8][4] = {};

    // slot element-offsets: slR = slot(T), slS = slot(T+2) (rotate mod 3)
    int slR = 0,         slR2 = 0;
    int slS = 2 * ASLOT, slS2 = 2 * BSLOT;

    // ---- prologue: stage tiles 0,1; retire tile 0 (vmcnt 12->6); publish.
#pragma unroll
    for (int j = 0; j < 4; ++j) async16(gA + j * rstep, lA + j * 2048);
#pragma unroll
    for (int j = 0; j < 2; ++j) async16(gB + j * rstep, lB + j * 2048);
    gA += BK; gB += BK;
#pragma unroll
    for (int j = 0; j < 4; ++j) async16(gA + j * rstep, lA + ASLOT + j * 2048);
#pragma unroll
    for (int j = 0; j < 2; ++j) async16(gB + j * rstep, lB + BSLOT + j * 2048);
    gA += BK; gB += BK;
    asm volatile("s_waitcnt vmcnt(6)" ::: "memory");
    __builtin_amdgcn_s_barrier();

#define TILE(DOSTAGE, VMN)                                                     \
  {                                                                            \
    short8 a[8], b[4];                                                         \
    a[0] = *(const short8*)(rdA0 + slR);                                       \
    _Pragma("unroll") for (int ni = 0; ni < 4; ++ni)                           \
        b[ni] = *(const short8*)(rdB0 + ni * 512 + slR2);                      \
    _Pragma("unroll") for (int mi = 1; mi < 8; ++mi)                           \
        a[mi] = *(const short8*)(rdA0 + mi * 512 + slR);                       \
    if (DOSTAGE) {                                                             \
      _Pragma("unroll") for (int j = 0; j < 4; ++j)                            \
          async16(gA + j * rstep, lA + slS + j * 2048);                        \
      _Pragma("unroll") for (int j = 0; j < 2; ++j)                            \
          async16(gB + j * rstep, lB + slS2 + j * 2048);                       \
      gA += BK; gB += BK;                                                      \
    }                                                                          \
    __builtin_amdgcn_s_setprio(1);                                             \
    _Pragma("unroll") for (int mi = 0; mi < 8; ++mi)                           \
      _Pragma("unroll") for (int ni = 0; ni < 4; ++ni)                         \
        acc[mi][ni] = __builtin_amdgcn_mfma_f32_16x16x32_bf16(                 \
            a[mi], b[ni], acc[mi][ni], 0, 0, 0);                               \
    __builtin_amdgcn_s_setprio(0);                                             \
    if ((VMN) == 6)      asm volatile("s_waitcnt vmcnt(6)" ::: "memory");      \
    else if ((VMN) == 0) asm volatile("s_waitcnt vmcnt(0)" ::: "memory");      \
    if ((VMN) >= 0) __builtin_amdgcn_s_barrier();                              \
    slR  = (slR  == 2 * ASLOT) ? 0 : slR  + ASLOT;                             \
    slR2 = (slR2 == 2 * BSLOT) ? 0 : slR2 + BSLOT;                             \
    slS  = (slS  == 2 * ASLOT) ? 0 : slS  + ASLOT;                             \
    slS2 = (slS2 == 2 * BSLOT) ? 0 : slS2 + BSLOT;                             \
  }

    // main loop: T = 0..NT-3 stage tiles 2..NT-1, counted vmcnt(6)
#pragma unroll 1
    for (int T = 0; T < NT - 2; ++T) {
        TILE(true, 6);
    }
    TILE(false, 0);    // T = NT-2: drain tile NT-1's loads
    TILE(false, -1);   // T = NT-1: no sync, fall through to epilogue

#undef TILE

    // epilogue: 16x16 C/D layout: col = lane&15, row = (lane>>4)*4 + reg
    const int col0 = bn * 128 + wn * 64 + (lane & 15);
    const int row0 = bm * 256 + wm * 128 + ((lane >> 4) * 4);
#pragma unroll
    for (int mi = 0; mi < 8; ++mi) {
#pragma unroll
        for (int ni = 0; ni < 4; ++ni) {
#pragma unroll
            for (int r = 0; r < 4; ++r) {
                int row = row0 + mi * 16 + r;
                C[(size_t)row * ldc + col0 + ni * 16] = (OutT)acc[mi][ni][r];
            }
        }
    }

    // ---- fused chunk-sum epilogue (QVG launch, V columns only) ----
    if (Sout && bn >= 8 && bn < 16) {
        const int p0 = (lane >> 4) * 4;            // intra-chunk base position
        const int bglob = bm >> 4;                 // batch (4096 rows = 16 bm)
        const int c0 = ((bm & 15) * 16 + wm * 8);  // chunk idx of mi=0
#pragma unroll
        for (int ni = 0; ni < 4; ++ni) {
            const int f = col0 + ni * 16 - 1024;   // v-feature index [0,1024)
            const float lam = lam_of(beta, f >> 6);
            const float l2g = __log2f(lam);
            float w[4];
#pragma unroll
            for (int r = 0; r < 4; ++r)
                w[r] = exp2f((float)(15 - p0 - r) * l2g);
#pragma unroll
            for (int mi = 0; mi < 8; ++mi) {
                float part = 0.0f;
#pragma unroll
                for (int r = 0; r < 4; ++r)
                    part = fmaf(w[r], acc[mi][ni][r], part);
                part += __shfl_xor(part, 16, 64);
                part += __shfl_xor(part, 32, 64);
                if (p0 == 0) {                     // lanes 0..15 write
                    const int cg = c0 + mi;
                    Sout[((size_t)bglob * NCHUNK + cg) * DD + f] = part;
                }
            }
        }
    }
}

// ---------------------------------------------------------------------------
// Serial carry over 256 chunks (R8's hierarchy measured WORSE; this is the
// floor). 16-wide load prefetch; next batch independent of the recurrence.
// ---------------------------------------------------------------------------
__global__ __launch_bounds__(64) void scan_carry(const float* __restrict__ S,
                                                 float* __restrict__ T,
                                                 const float* __restrict__ beta) {
    const int gid = blockIdx.x * 64 + threadIdx.x;  // 0..4095
    const int b = gid >> 10;
    const int f = gid & 1023;
    const float lam  = lam_of(beta, f >> 6);
    const float lamC = powf(lam, (float)SCC);

    const size_t base = (size_t)b * NCHUNK * DD + f;

    float v[16];
#pragma unroll
    for (int j = 0; j < 16; ++j) v[j] = S[base + (size_t)j * DD];

    float t = 0.0f;
    for (int c0 = 0; c0 < NCHUNK; c0 += 16) {
        float cur[16];
#pragma unroll
        for (int j = 0; j < 16; ++j) cur[j] = v[j];
        if (c0 + 16 < NCHUNK) {
#pragma unroll
            for (int j = 0; j < 16; ++j)
                v[j] = S[base + (size_t)(c0 + 16 + j) * DD];
        }
#pragma unroll
        for (int j = 0; j < 16; ++j) {
            T[base + (size_t)(c0 + j) * DD] = t;
            t = fmaf(t, lamC, cur[j]);
        }
    }
}

// ---------------------------------------------------------------------------
// Fused: re-scan chunk from carry T -> ret (kept in LDS), per-row LayerNorm,
// SiLU gate, write z (bf16, contiguous [M,1024]). ret never touches HBM.
// R10 restructure for latency: 256 threads = 4 waves (16 waves/CU at 4
// blocks/CU, was 8); phase 1 narrowed to 4 features/thread (same serial
// depth, half per-step work, depth-2 prefetch); phase 2 rows split across
// 4 waves (4 rows each, was 8); ALL gate loads (32B/thread) issued as a
// prefetch burst BEFORE phase 1 so their latency hides under the serial
// scan. grid (NCHUNK, BB). LDS 16x1024 bf16 = 32KB.
// ---------------------------------------------------------------------------
__global__ __launch_bounds__(256) void scan_apply_ln(const bf16* __restrict__ qvg,
                                                     const float* __restrict__ beta,
                                                     const float* __restrict__ T,
                                                     const float* __restrict__ gamma,
                                                     const float* __restrict__ betaln,
                                                     bf16* __restrict__ z) {
    __shared__ bf16 lds_ret[SCC][DD];   // 32 KB

    const int c    = blockIdx.x;
    const int b    = blockIdx.y;
    const int tid  = threadIdx.x;       // 0..255
    const int lane = tid & 63;
    const int wv   = tid >> 6;          // 0..3

    const bf16* qvg0 = qvg + ((size_t)(b * LL + c * SCC)) * LDQVG;

    // ---- gate prefetch burst (phase-2 data, independent of phase 1):
    // wave wv handles rows wv, wv+4, wv+8, wv+12.
    bf8 gAp[4], gBp[4];
#pragma unroll
    for (int i = 0; i < 4; ++i) {
        const bf16* gp = qvg0 + (size_t)(wv + 4 * i) * LDQVG + 2048 + lane * 8;
        gAp[i] = *(const bf8*)(gp);
        gBp[i] = *(const bf8*)(gp + 512);
    }

    // ---- phase 1: local scan from carry, ret -> LDS. 4 features/thread.
    const int f0 = tid * 4;
    const float lam = lam_of(beta, f0 >> 6);

    const float* tp = T + ((size_t)(b * NCHUNK + c)) * DD + f0;
    float4 tv = *(const float4*)(tp);
    float s[4] = {tv.x, tv.y, tv.z, tv.w};

    const bf16* qp = qvg0 + f0;
    bf4 vbuf[2], qbuf[2];
    vbuf[0] = *(const bf4*)(qp + 1024);
    qbuf[0] = *(const bf4*)(qp);
    vbuf[1] = *(const bf4*)(qp + 1024 + LDQVG);
    qbuf[1] = *(const bf4*)(qp + LDQVG);
#pragma unroll
    for (int t = 0; t < SCC; ++t) {
        bf4 vv = vbuf[t & 1];
        bf4 qq = qbuf[t & 1];
        if (t + 2 < SCC) {
            const size_t offn = (size_t)(t + 2) * LDQVG;
            vbuf[t & 1] = *(const bf4*)(qp + 1024 + offn);
            qbuf[t & 1] = *(const bf4*)(qp + offn);
        }
        bf4 o;
#pragma unroll
        for (int j = 0; j < 4; ++j) {
            s[j] = fmaf(s[j], lam, b2f(vv.e[j]));
            o.e[j] = __float2bfloat16(b2f(qq.e[j]) * s[j]);
        }
        *(bf4*)(&lds_ret[t][f0]) = o;
    }
    __syncthreads();

    // ---- phase 2: per-row LN + SiLU gate. wave wv does rows wv, wv+4, ...
    // cache gamma/beta for this lane's two feature groups (lane*8, 512+lane*8)
    float gmA[8], btA[8], gmB[8], btB[8];
#pragma unroll
    for (int j = 0; j < 8; j += 4) {
        *(float4*)(gmA + j) = *(const float4*)(gamma  + lane * 8 + j);
        *(float4*)(btA + j) = *(const float4*)(betaln + lane * 8 + j);
        *(float4*)(gmB + j) = *(const float4*)(gamma  + 512 + lane * 8 + j);
        *(float4*)(btB + j) = *(const float4*)(betaln + 512 + lane * 8 + j);
    }

#pragma unroll
    for (int i = 0; i < 4; ++i) {
        const int t = wv + 4 * i;
        bf8 rA = *(const bf8*)(&lds_ret[t][lane * 8]);
        bf8 rB = *(const bf8*)(&lds_ret[t][512 + lane * 8]);

        float xa[8], xb2[8];
        float sum = 0.f, sq = 0.f;
#pragma unroll
        for (int j = 0; j < 8; ++j) {
            xa[j]  = b2f(rA.e[j]);
            xb2[j] = b2f(rB.e[j]);
            sum += xa[j] + xb2[j];
            sq  += xa[j] * xa[j] + xb2[j] * xb2[j];
        }
#pragma unroll
        for (int off = 32; off >= 1; off >>= 1) {
            sum += __shfl_xor(sum, off, 64);
            sq  += __shfl_xor(sq,  off, 64);
        }
        const float mu   = sum * (1.0f / DD);
        const float var  = sq * (1.0f / DD) - mu * mu;
        const float rstd = rsqrtf(var + LN_EPS);

        bf8 oA, oB;
#pragma unroll
        for (int j = 0; j < 8; ++j) {
            float ya = (xa[j]  - mu) * rstd * gmA[j] + btA[j];
            float yb = (xb2[j] - mu) * rstd * gmB[j] + btB[j];
            float ga = b2f(gAp[i].e[j]);
            float gb = b2f(gBp[i].e[j]);
            oA.e[j] = __float2bfloat16(ya * (ga / (1.0f + expf(-ga))));
            oB.e[j] = __float2bfloat16(yb * (gb / (1.0f + expf(-gb))));
        }
        const size_t row = (size_t)(b * LL + c * SCC + t);
        bf16* zp = z + row * DD + lane * 8;
        *(bf8*)(zp)       = oA;
        *(bf8*)(zp + 512) = oB;
    }
}

// ---------------------------------------------------------------------------
// launch
// ---------------------------------------------------------------------------
extern "C" void kernel_launch(void* const* d_in, const int* in_sizes, int n_in,
                              void* d_out, int out_size, void* d_ws, size_t ws_size,
                              hipStream_t stream) {
    const float* x     = (const float*)d_in[0];
    const float* Wq    = (const float*)d_in[1];
    const float* Wv    = (const float*)d_in[2];
    const float* Wo    = (const float*)d_in[3];
    const float* Wg    = (const float*)d_in[4];
    const float* beta  = (const float*)d_in[5];
    const float* ln_g  = (const float*)d_in[6];
    const float* ln_b  = (const float*)d_in[7];
    float* out = (float*)d_out;

    char* ws = (char*)d_ws;
    // workspace (136MB, time-multiplexed):
    //   @0    : xb 32MB (cvt -> QVG GEMM) -> zb 32MB (apply_ln -> final GEMM)
    //   @32MB : wqb 6MB (wq|wv|wg; dead after QVG GEMM) -> Tbuf 4MB
    //   @38MB : wob 2MB (live until final GEMM)
    //   @40MB : qvg 96MB [M,3072] = q|v|g per row
    // S (4MB f32) lives in d_out: written by QVG epilogue, consumed by carry,
    // dead before the final GEMM overwrites all of out.
    bf16*  xb   = (bf16*)ws;
    bf16*  wqb  = (bf16*)(ws + (size_t)32 * 1024 * 1024);
    float* Tbuf = (float*)(ws + (size_t)32 * 1024 * 1024);     // alias wqb (dead)
    bf16*  wob  = wqb + 3 * 1048576;
    bf16*  qvg  = (bf16*)(ws + (size_t)40 * 1024 * 1024);
    bf16*  zb   = xb;
    float* Sbuf = out;                                         // scratch in d_out

    // all dtype conversions in one dispatch (x + 4 weights)
    cvt_all<<<dim3(16384 + 4096), dim3(256), 0, stream>>>(x, Wq, Wv, Wg, Wo, xb, wqb);

    // fused QVG GEMM: [M,1024] x [3072,1024]^T -> [M,3072]; V-blocks also
    // emit chunk sums S directly from f32 accumulators.
    gemm_ring<bf16, DD><<<dim3(MM / 256, LDQVG / 128), dim3(256), 0, stream>>>(
        xb, wqb, qvg, LDQVG, Sbuf, beta);

    // carry scan over chunks, then fused re-scan + LN + gate
    scan_carry<<<dim3(64), dim3(64), 0, stream>>>(Sbuf, Tbuf, beta);
    scan_apply_ln<<<dim3(NCHUNK, BB), dim3(256), 0, stream>>>(
        qvg, beta, Tbuf, ln_g, ln_b, zb);

    // final GEMM: [M,1024] x [1024,1024]^T -> [M,1024] f32 (overwrites out)
    gemm_ring<float, DD><<<dim3(MM / 256, DD / 128), dim3(256), 0, stream>>>(
        zb, wob, out, DD, nullptr, nullptr);
}